// Round 4
// baseline (87622.723 us; speedup 1.0000x reference)
//
#include <hip/hip_runtime.h>
#include <cstdint>
#include <cstddef>

// Problem constants
constexpr int Hh = 51;       // hidden size
constexpr int Tt = 2048;     // timesteps
constexpr int Bb = 8192;     // batch
constexpr int NBATCH = 32;   // batch elements per block
constexpr int PAD = 52;      // padded h-row stride (floats), 16B aligned
constexpr int NTH = 512;     // 8 waves/block, grid = 256 blocks -> 1 block/CU

__device__ __forceinline__ float sigmoidf_(float x) {
    return __builtin_amdgcn_rcpf(1.0f + __expf(-x));
}

__device__ __forceinline__ float tanhf_(float x) {
    const float a = fabsf(x);
    const float e = __expf(-2.0f * a);
    const float r = (1.0f - e) * __builtin_amdgcn_rcpf(1.0f + e);
    return copysignf(r, x);
}

__device__ __forceinline__ float lstm_update(float ai, float af, float ag, float ao, float& c) {
    const float si = sigmoidf_(ai);
    const float sf = sigmoidf_(af);
    const float tg = tanhf_(ag);
    const float so = sigmoidf_(ao);
    c = fmaf(sf, c, si * tg);
    return so * tanhf_(c);
}

// ---- per-phase helpers ----------------------------------------------------
// NU = units handled by this lane's group (loop bound; real count = ucnt <= NU,
// extra acc rows are clamped duplicates, guarded at the write).

template<int NU>
__device__ __forceinline__ void do_layer1(
    const float* __restrict__ W1p, const float* __restrict__ hb,
    float* __restrict__ h1w, int b, int ustart, int ucnt,
    const int* __restrict__ rowoff1, const float* __restrict__ xw,
    const float* __restrict__ bb1, float x, float* __restrict__ c1)
{
    constexpr int NA = 4 * NU;
    float acc[NA];
    #pragma unroll
    for (int r = 0; r < NA; ++r) acc[r] = fmaf(x, xw[r], bb1[r]);

    #pragma unroll
    for (int kb = 0; kb < 13; ++kb) {
        const float4 hv = *(const float4*)(hb + kb * 4);
        #pragma unroll
        for (int r = 0; r < NA; ++r) {
            const float4 w4 = *(const float4*)(W1p + rowoff1[r] + kb * 4);
            acc[r] = fmaf(w4.x, hv.x, acc[r]);
            acc[r] = fmaf(w4.y, hv.y, acc[r]);
            acc[r] = fmaf(w4.z, hv.z, acc[r]);
            acc[r] = fmaf(w4.w, hv.w, acc[r]);
        }
    }
    #pragma unroll
    for (int u = 0; u < NU; ++u) {
        if (u < ucnt) {
            const float hn = lstm_update(acc[u*4], acc[u*4+1], acc[u*4+2], acc[u*4+3], c1[u]);
            h1w[b * PAD + ustart + u] = hn;
        }
    }
}

template<int NU>
__device__ __forceinline__ void do_layer2(
    const float* __restrict__ W2p, const float* __restrict__ ha, const float* __restrict__ hbv,
    float* __restrict__ h2w, int b, int ustart, int ucnt,
    const int* __restrict__ rowoff2, const float* __restrict__ bb2, float* __restrict__ c2)
{
    constexpr int NA = 4 * NU;
    float acc[NA];
    #pragma unroll
    for (int r = 0; r < NA; ++r) acc[r] = bb2[r];

    #pragma unroll
    for (int kb = 0; kb < 13; ++kb) {
        const float4 va = *(const float4*)(ha  + kb * 4);
        const float4 vb = *(const float4*)(hbv + kb * 4);
        #pragma unroll
        for (int r = 0; r < NA; ++r) {
            const float4 wa = *(const float4*)(W2p + rowoff2[r] + kb * 4);
            const float4 wb = *(const float4*)(W2p + rowoff2[r] + 52 + kb * 4);
            acc[r] = fmaf(wa.x, va.x, acc[r]);
            acc[r] = fmaf(wa.y, va.y, acc[r]);
            acc[r] = fmaf(wa.z, va.z, acc[r]);
            acc[r] = fmaf(wa.w, va.w, acc[r]);
            acc[r] = fmaf(wb.x, vb.x, acc[r]);
            acc[r] = fmaf(wb.y, vb.y, acc[r]);
            acc[r] = fmaf(wb.z, vb.z, acc[r]);
            acc[r] = fmaf(wb.w, vb.w, acc[r]);
        }
    }
    #pragma unroll
    for (int u = 0; u < NU; ++u) {
        if (u < ucnt) {
            const float hn = lstm_update(acc[u*4], acc[u*4+1], acc[u*4+2], acc[u*4+3], c2[u]);
            h2w[b * PAD + ustart + u] = hn;
        }
    }
}

// ---- main kernel ----------------------------------------------------------
// Block: 32 batches, 512 threads = 8 waves = 16 half-wave groups.
// Group g = (lane>>5)*8 + wid owns 3-4 units; lane&31 = batch.
__global__ __launch_bounds__(NTH, 2)
void lstm2(const float* __restrict__ xin,
           const float* __restrict__ W1p, const float* __restrict__ W2p,
           const float* __restrict__ wx1, const float* __restrict__ bs1,
           const float* __restrict__ bs2,
           const float* __restrict__ Wlin, const float* __restrict__ blin,
           float* __restrict__ yout, int transposed)
{
    __shared__ __align__(16) float sh[4 * NBATCH * PAD]; // 26.6 KB
    float* h1buf = sh;
    float* h2buf = sh + 2 * NBATCH * PAD;

    const int tid  = threadIdx.x;
    const int lane = tid & 63;
    const int wid  = tid >> 6;
    const int widu = __builtin_amdgcn_readfirstlane(wid);
    const int half = lane >> 5;
    const int b    = lane & 31;
    const int g    = half * 8 + wid;                 // 0..15
    const int ucnt   = (g < 3) ? 4 : 3;
    const int ustart = (g < 3) ? 4 * g : 3 * g + 3;  // covers units 0..50
    const int gb   = blockIdx.x * NBATCH + b;

    for (int i = tid; i < 4 * NBATCH * PAD; i += NTH) sh[i] = 0.0f;

    // per-lane row constants (weights stay in L2; biases/Wih1 cached in VGPRs)
    int rowoff1[16], rowoff2[16];
    float xw[16], bb1[16], bb2[16];
    #pragma unroll
    for (int u = 0; u < 4; ++u) {
        const int uc = (u < ucnt) ? u : (ucnt - 1);  // clamp duplicate (guarded at write)
        const int j  = ustart + uc;
        #pragma unroll
        for (int gt = 0; gt < 4; ++gt) {
            const int r   = u * 4 + gt;
            const int row = gt * Hh + j;
            rowoff1[r] = row * 52;
            rowoff2[r] = row * 104;
            xw[r]  = wx1[row];
            bb1[r] = bs1[row];
            bb2[r] = bs2[row];
        }
    }

    float c1[4], c2[4];
    #pragma unroll
    for (int i = 0; i < 4; ++i) { c1[i] = 0.0f; c2[i] = 0.0f; }

    const float bl = blin[0];
    __syncthreads();

    for (int t = 0; t < Tt; ++t) {
        const int pr = t & 1;
        const int pw = pr ^ 1;
        float* __restrict__ h1r = h1buf + pr * NBATCH * PAD;
        float* __restrict__ h1w = h1buf + pw * NBATCH * PAD;
        float* __restrict__ h2r = h2buf + pr * NBATCH * PAD;
        float* __restrict__ h2w = h2buf + pw * NBATCH * PAD;

        const float x = transposed ? xin[(size_t)t * Bb + gb]
                                   : xin[(size_t)gb * Tt + t];

        if (widu < 3) do_layer1<4>(W1p, h1r + b * PAD, h1w, b, ustart, ucnt, rowoff1, xw, bb1, x, c1);
        else          do_layer1<3>(W1p, h1r + b * PAD, h1w, b, ustart, ucnt, rowoff1, xw, bb1, x, c1);
        __syncthreads();

        if (widu < 3) do_layer2<4>(W2p, h1w + b * PAD, h2r + b * PAD, h2w, b, ustart, ucnt, rowoff2, bb2, c2);
        else          do_layer2<3>(W2p, h1w + b * PAD, h2r + b * PAD, h2w, b, ustart, ucnt, rowoff2, bb2, c2);
        __syncthreads();

        // output projection: lanes 0..31 of wave 0 (Wlin is wave-uniform -> s_load)
        if (tid < 32) {
            const float* hy = h2w + tid * PAD;
            float a = bl;
            #pragma unroll
            for (int kb = 0; kb < 12; ++kb) {
                const float4 hv = *(const float4*)(hy + kb * 4);
                a = fmaf(Wlin[kb*4    ], hv.x, a);
                a = fmaf(Wlin[kb*4 + 1], hv.y, a);
                a = fmaf(Wlin[kb*4 + 2], hv.z, a);
                a = fmaf(Wlin[kb*4 + 3], hv.w, a);
            }
            a = fmaf(Wlin[48], hy[48], a);
            a = fmaf(Wlin[49], hy[49], a);
            a = fmaf(Wlin[50], hy[50], a);
            const int gby = blockIdx.x * NBATCH + tid;
            if (transposed) yout[(size_t)t * Bb + gby] = a;
            else            yout[(size_t)gby * Tt + t] = a;
        }
        // safe without a 3rd barrier: y reads h2w(t); next write to that buffer
        // is L2(t+2), which is ordered after barrier1(t+1) > all of y(t).
    }
}

// Pack weights into 16B-aligned zero-padded rows in d_ws:
//   W1p[row][52]  = Whh1 row (51) + 0-pad
//   W2p[row][104] = Wih2 row (51) + 0 | Whh2 row (51) + 0
//   wx1/bs1/bs2[204] per-row scalars
__global__ __launch_bounds__(64)
void pack_weights(const float* __restrict__ Wih1, const float* __restrict__ Whh1,
                  const float* __restrict__ bih1, const float* __restrict__ bhh1,
                  const float* __restrict__ Wih2, const float* __restrict__ Whh2,
                  const float* __restrict__ bih2, const float* __restrict__ bhh2,
                  float* __restrict__ W1p, float* __restrict__ W2p,
                  float* __restrict__ wx1, float* __restrict__ bs1, float* __restrict__ bs2)
{
    const int row = blockIdx.x;   // 0..203
    const int k   = threadIdx.x;  // 0..63
    if (k < 52) {
        W1p[row * 52 + k]        = (k < Hh) ? Whh1[row * Hh + k] : 0.0f;
        W2p[row * 104 + k]       = (k < Hh) ? Wih2[row * Hh + k] : 0.0f;
        W2p[row * 104 + 52 + k]  = (k < Hh) ? Whh2[row * Hh + k] : 0.0f;
    }
    if (k == 0) {
        wx1[row] = Wih1[row];
        bs1[row] = bih1[row] + bhh1[row];
        bs2[row] = bih2[row] + bhh2[row];
    }
}

// Tiled transpose: src[R][C] -> dst[C][R]; R, C multiples of 64.
__global__ __launch_bounds__(512)
void transpose_k(const float* __restrict__ src, float* __restrict__ dst, int R, int C)
{
    __shared__ float tile[64][65];
    const int c0 = blockIdx.x * 64;
    const int r0 = blockIdx.y * 64;
    const int tx = threadIdx.x;
    const int ty = threadIdx.y;
    #pragma unroll
    for (int i = 0; i < 64; i += 8)
        tile[ty + i][tx] = src[(size_t)(r0 + ty + i) * C + (c0 + tx)];
    __syncthreads();
    #pragma unroll
    for (int i = 0; i < 64; i += 8)
        dst[(size_t)(c0 + ty + i) * R + (r0 + tx)] = tile[tx][ty + i];
}

extern "C" void kernel_launch(void* const* d_in, const int* in_sizes, int n_in,
                              void* d_out, int out_size, void* d_ws, size_t ws_size,
                              hipStream_t stream)
{
    const float* input = (const float*)d_in[0];
    const float* Wih1  = (const float*)d_in[1];
    const float* Whh1  = (const float*)d_in[2];
    const float* bih1  = (const float*)d_in[3];
    const float* bhh1  = (const float*)d_in[4];
    const float* Wih2  = (const float*)d_in[5];
    const float* Whh2  = (const float*)d_in[6];
    const float* bih2  = (const float*)d_in[7];
    const float* bhh2  = (const float*)d_in[8];
    const float* Wlin  = (const float*)d_in[9];
    const float* blin  = (const float*)d_in[10];
    float* out = (float*)d_out;

    const size_t TB = (size_t)Bb * Tt;
    // float offsets within ws
    const size_t offW1p = 2 * TB;                 // big layout (with transposes)
    const size_t packFloats = 204 * 52 + 204 * 104 + 3 * 204;
    const size_t needBig   = (2 * TB + packFloats) * sizeof(float);
    const size_t needSmall = packFloats * sizeof(float);

    float* ws = (float*)d_ws;

    if (ws_size >= needBig) {
        float* xT   = ws;
        float* yT   = ws + TB;
        float* W1p  = ws + offW1p;
        float* W2p  = W1p + 204 * 52;
        float* wx1  = W2p + 204 * 104;
        float* bs1  = wx1 + 204;
        float* bs2  = bs1 + 204;

        pack_weights<<<204, 64, 0, stream>>>(Wih1, Whh1, bih1, bhh1,
                                             Wih2, Whh2, bih2, bhh2,
                                             W1p, W2p, wx1, bs1, bs2);
        transpose_k<<<dim3(Tt / 64, Bb / 64), dim3(64, 8), 0, stream>>>(input, xT, Bb, Tt);
        lstm2<<<dim3(Bb / NBATCH), dim3(NTH), 0, stream>>>(
            xT, W1p, W2p, wx1, bs1, bs2, Wlin, blin, yT, 1);
        transpose_k<<<dim3(Bb / 64, Tt / 64), dim3(64, 8), 0, stream>>>(yT, out, Tt, Bb);
    } else {
        // fallback: packed weights only, strided x/y access
        float* W1p  = ws;
        float* W2p  = W1p + 204 * 52;
        float* wx1  = W2p + 204 * 104;
        float* bs1  = wx1 + 204;
        float* bs2  = bs1 + 204;
        (void)needSmall;

        pack_weights<<<204, 64, 0, stream>>>(Wih1, Whh1, bih1, bhh1,
                                             Wih2, Whh2, bih2, bhh2,
                                             W1p, W2p, wx1, bs1, bs2);
        lstm2<<<dim3(Bb / NBATCH), dim3(NTH), 0, stream>>>(
            input, W1p, W2p, wx1, bs1, bs2, Wlin, blin, out, 0);
    }
}

// Round 5
// 31004.932 us; speedup vs baseline: 2.8261x; 2.8261x over previous
//
#include <hip/hip_runtime.h>
#include <cstdint>
#include <cstddef>

// Problem constants
constexpr int Hh = 51;       // hidden size
constexpr int Tt = 2048;     // timesteps
constexpr int Bb = 8192;     // batch
constexpr int NBATCH = 32;   // batch elements per block
constexpr int PAD = 52;      // padded h-row stride (floats), 16B aligned
constexpr int NTH = 512;     // 8 waves/block, grid = 256 blocks -> 1 block/CU

// LDS float offsets (dynamic LDS, total 38480 floats = 153,920 B <= 160 KiB/CU)
constexpr int LDS_W1   = 0;                    // 204*52  = 10608 floats
constexpr int LDS_W2   = 204 * 52;             // 204*104 = 21216 floats
constexpr int LDS_H    = LDS_W2 + 204 * 104;   // 4*32*52 =  6656 floats
constexpr int LDS_TOT  = LDS_H + 4 * NBATCH * PAD;

__device__ __forceinline__ float sigmoidf_(float x) {
    return __builtin_amdgcn_rcpf(1.0f + __expf(-x));
}

__device__ __forceinline__ float tanhf_(float x) {
    const float a = fabsf(x);
    const float e = __expf(-2.0f * a);
    const float r = (1.0f - e) * __builtin_amdgcn_rcpf(1.0f + e);
    return copysignf(r, x);
}

__device__ __forceinline__ float lstm_update(float ai, float af, float ag, float ao, float& c) {
    const float si = sigmoidf_(ai);
    const float sf = sigmoidf_(af);
    const float tg = tanhf_(ag);
    const float so = sigmoidf_(ao);
    c = fmaf(sf, c, si * tg);
    return so * tanhf_(c);
}

// ---- per-phase helpers ----------------------------------------------------
// Weights now come from LDS (broadcast reads: same address across each
// 32-lane half-wave -> conflict-free). NU = compile-time unit loop bound.

template<int NU>
__device__ __forceinline__ void do_layer1(
    const float* __restrict__ W1s, const float* __restrict__ hb,
    float* __restrict__ h1w, int b, int ustart, int ucnt,
    const int* __restrict__ rowoff1, const float* __restrict__ xw,
    const float* __restrict__ bb1, float x, float* __restrict__ c1)
{
    constexpr int NA = 4 * NU;
    float acc[NA];
    #pragma unroll
    for (int r = 0; r < NA; ++r) acc[r] = fmaf(x, xw[r], bb1[r]);

    #pragma unroll
    for (int kb = 0; kb < 13; ++kb) {
        const float4 hv = *(const float4*)(hb + kb * 4);
        #pragma unroll
        for (int r = 0; r < NA; ++r) {
            const float4 w4 = *(const float4*)(W1s + rowoff1[r] + kb * 4);
            acc[r] = fmaf(w4.x, hv.x, acc[r]);
            acc[r] = fmaf(w4.y, hv.y, acc[r]);
            acc[r] = fmaf(w4.z, hv.z, acc[r]);
            acc[r] = fmaf(w4.w, hv.w, acc[r]);
        }
    }
    #pragma unroll
    for (int u = 0; u < NU; ++u) {
        if (u < ucnt) {
            const float hn = lstm_update(acc[u*4], acc[u*4+1], acc[u*4+2], acc[u*4+3], c1[u]);
            h1w[b * PAD + ustart + u] = hn;
        }
    }
}

template<int NU>
__device__ __forceinline__ void do_layer2(
    const float* __restrict__ W2s, const float* __restrict__ ha, const float* __restrict__ hbv,
    float* __restrict__ h2w, int b, int ustart, int ucnt,
    const int* __restrict__ rowoff2, const float* __restrict__ bb2, float* __restrict__ c2)
{
    constexpr int NA = 4 * NU;
    float acc[NA];
    #pragma unroll
    for (int r = 0; r < NA; ++r) acc[r] = bb2[r];

    #pragma unroll
    for (int kb = 0; kb < 13; ++kb) {
        const float4 va = *(const float4*)(ha  + kb * 4);
        const float4 vb = *(const float4*)(hbv + kb * 4);
        #pragma unroll
        for (int r = 0; r < NA; ++r) {
            const float4 wa = *(const float4*)(W2s + rowoff2[r] + kb * 4);
            const float4 wb = *(const float4*)(W2s + rowoff2[r] + 52 + kb * 4);
            acc[r] = fmaf(wa.x, va.x, acc[r]);
            acc[r] = fmaf(wa.y, va.y, acc[r]);
            acc[r] = fmaf(wa.z, va.z, acc[r]);
            acc[r] = fmaf(wa.w, va.w, acc[r]);
            acc[r] = fmaf(wb.x, vb.x, acc[r]);
            acc[r] = fmaf(wb.y, vb.y, acc[r]);
            acc[r] = fmaf(wb.z, vb.z, acc[r]);
            acc[r] = fmaf(wb.w, vb.w, acc[r]);
        }
    }
    #pragma unroll
    for (int u = 0; u < NU; ++u) {
        if (u < ucnt) {
            const float hn = lstm_update(acc[u*4], acc[u*4+1], acc[u*4+2], acc[u*4+3], c2[u]);
            h2w[b * PAD + ustart + u] = hn;
        }
    }
}

// ---- main kernel ----------------------------------------------------------
// Block: 32 batches, 512 threads = 8 waves = 16 half-wave groups.
// Group g = (lane>>5)*8 + wid owns 3-4 units; lane&31 = batch.
// Weights live in LDS (loaded once); h1/h2 double-buffered in LDS.
__global__ __launch_bounds__(NTH, 2)
void lstm2(const float* __restrict__ xin,
           const float* __restrict__ W1p, const float* __restrict__ W2p,
           const float* __restrict__ wx1, const float* __restrict__ bs1,
           const float* __restrict__ bs2,
           const float* __restrict__ Wlin, const float* __restrict__ blin,
           float* __restrict__ yout, int transposed)
{
    extern __shared__ __align__(16) float dynls[];
    const float* W1s = dynls + LDS_W1;
    const float* W2s = dynls + LDS_W2;
    float* h1buf = dynls + LDS_H;
    float* h2buf = dynls + LDS_H + 2 * NBATCH * PAD;

    const int tid  = threadIdx.x;
    const int lane = tid & 63;
    const int wid  = tid >> 6;
    const int widu = __builtin_amdgcn_readfirstlane(wid);
    const int half = lane >> 5;
    const int b    = lane & 31;
    const int g    = half * 8 + wid;                 // 0..15
    const int ucnt   = (g < 3) ? 4 : 3;
    const int ustart = (g < 3) ? 4 * g : 3 * g + 3;  // covers units 0..50
    const int gb   = blockIdx.x * NBATCH + b;

    // one-time: copy packed weights (contiguous W1p|W2p = 31824 floats) to LDS
    {
        const float4* src = (const float4*)W1p;          // W2p immediately follows
        float4* dst = (float4*)(dynls);
        for (int i = tid; i < (204 * 52 + 204 * 104) / 4; i += NTH)
            dst[i] = src[i];
    }
    // zero h buffers
    for (int i = tid; i < 4 * NBATCH * PAD; i += NTH) dynls[LDS_H + i] = 0.0f;

    // per-lane row constants (biases/Wih1 cached in VGPRs)
    int rowoff1[16], rowoff2[16];
    float xw[16], bb1[16], bb2[16];
    #pragma unroll
    for (int u = 0; u < 4; ++u) {
        const int uc = (u < ucnt) ? u : (ucnt - 1);  // clamp duplicate (guarded at write)
        const int j  = ustart + uc;
        #pragma unroll
        for (int gt = 0; gt < 4; ++gt) {
            const int r   = u * 4 + gt;
            const int row = gt * Hh + j;
            rowoff1[r] = row * 52;
            rowoff2[r] = row * 104;
            xw[r]  = wx1[row];
            bb1[r] = bs1[row];
            bb2[r] = bs2[row];
        }
    }

    float c1[4], c2[4];
    #pragma unroll
    for (int i = 0; i < 4; ++i) { c1[i] = 0.0f; c2[i] = 0.0f; }

    const float bl = blin[0];
    __syncthreads();

    // prefetch x(0)
    float xcur = transposed ? xin[gb] : xin[(size_t)gb * Tt];

    for (int t = 0; t < Tt; ++t) {
        const int pr = t & 1;
        const int pw = pr ^ 1;
        float* __restrict__ h1r = h1buf + pr * NBATCH * PAD;
        float* __restrict__ h1w = h1buf + pw * NBATCH * PAD;
        float* __restrict__ h2r = h2buf + pr * NBATCH * PAD;
        float* __restrict__ h2w = h2buf + pw * NBATCH * PAD;

        // prefetch x(t+1): issued here, consumed next iteration (hides HBM/L2 latency)
        float xnext = 0.0f;
        if (t + 1 < Tt)
            xnext = transposed ? xin[(size_t)(t + 1) * Bb + gb]
                               : xin[(size_t)gb * Tt + (t + 1)];

        if (widu < 3) do_layer1<4>(W1s, h1r + b * PAD, h1w, b, ustart, ucnt, rowoff1, xw, bb1, xcur, c1);
        else          do_layer1<3>(W1s, h1r + b * PAD, h1w, b, ustart, ucnt, rowoff1, xw, bb1, xcur, c1);
        __syncthreads();

        if (widu < 3) do_layer2<4>(W2s, h1w + b * PAD, h2r + b * PAD, h2w, b, ustart, ucnt, rowoff2, bb2, c2);
        else          do_layer2<3>(W2s, h1w + b * PAD, h2r + b * PAD, h2w, b, ustart, ucnt, rowoff2, bb2, c2);
        __syncthreads();

        // output projection: lanes 0..31 of wave 0 (Wlin wave-uniform -> scalar path)
        if (tid < 32) {
            const float* hy = h2w + tid * PAD;
            float a = bl;
            #pragma unroll
            for (int kb = 0; kb < 12; ++kb) {
                const float4 hv = *(const float4*)(hy + kb * 4);
                a = fmaf(Wlin[kb*4    ], hv.x, a);
                a = fmaf(Wlin[kb*4 + 1], hv.y, a);
                a = fmaf(Wlin[kb*4 + 2], hv.z, a);
                a = fmaf(Wlin[kb*4 + 3], hv.w, a);
            }
            a = fmaf(Wlin[48], hy[48], a);
            a = fmaf(Wlin[49], hy[49], a);
            a = fmaf(Wlin[50], hy[50], a);
            const int gby = blockIdx.x * NBATCH + tid;
            if (transposed) yout[(size_t)t * Bb + gby] = a;
            else            yout[(size_t)gby * Tt + t] = a;
        }
        // safe without a 3rd barrier: y reads h2w(t); next write to that buffer
        // is L2(t+2), which is ordered after barrier1(t+1) > all of y(t).
        xcur = xnext;
    }
}

// Pack weights into 16B-aligned zero-padded rows in d_ws:
//   W1p[row][52]  = Whh1 row (51) + 0-pad
//   W2p[row][104] = Wih2 row (51) + 0 | Whh2 row (51) + 0   (contiguous after W1p)
//   wx1/bs1/bs2[204] per-row scalars
__global__ __launch_bounds__(64)
void pack_weights(const float* __restrict__ Wih1, const float* __restrict__ Whh1,
                  const float* __restrict__ bih1, const float* __restrict__ bhh1,
                  const float* __restrict__ Wih2, const float* __restrict__ Whh2,
                  const float* __restrict__ bih2, const float* __restrict__ bhh2,
                  float* __restrict__ W1p, float* __restrict__ W2p,
                  float* __restrict__ wx1, float* __restrict__ bs1, float* __restrict__ bs2)
{
    const int row = blockIdx.x;   // 0..203
    const int k   = threadIdx.x;  // 0..63
    if (k < 52) {
        W1p[row * 52 + k]        = (k < Hh) ? Whh1[row * Hh + k] : 0.0f;
        W2p[row * 104 + k]       = (k < Hh) ? Wih2[row * Hh + k] : 0.0f;
        W2p[row * 104 + 52 + k]  = (k < Hh) ? Whh2[row * Hh + k] : 0.0f;
    }
    if (k == 0) {
        wx1[row] = Wih1[row];
        bs1[row] = bih1[row] + bhh1[row];
        bs2[row] = bih2[row] + bhh2[row];
    }
}

// Tiled transpose: src[R][C] -> dst[C][R]; R, C multiples of 64.
__global__ __launch_bounds__(512)
void transpose_k(const float* __restrict__ src, float* __restrict__ dst, int R, int C)
{
    __shared__ float tile[64][65];
    const int c0 = blockIdx.x * 64;
    const int r0 = blockIdx.y * 64;
    const int tx = threadIdx.x;
    const int ty = threadIdx.y;
    #pragma unroll
    for (int i = 0; i < 64; i += 8)
        tile[ty + i][tx] = src[(size_t)(r0 + ty + i) * C + (c0 + tx)];
    __syncthreads();
    #pragma unroll
    for (int i = 0; i < 64; i += 8)
        dst[(size_t)(c0 + ty + i) * R + (r0 + tx)] = tile[tx][ty + i];
}

extern "C" void kernel_launch(void* const* d_in, const int* in_sizes, int n_in,
                              void* d_out, int out_size, void* d_ws, size_t ws_size,
                              hipStream_t stream)
{
    const float* input = (const float*)d_in[0];
    const float* Wih1  = (const float*)d_in[1];
    const float* Whh1  = (const float*)d_in[2];
    const float* bih1  = (const float*)d_in[3];
    const float* bhh1  = (const float*)d_in[4];
    const float* Wih2  = (const float*)d_in[5];
    const float* Whh2  = (const float*)d_in[6];
    const float* bih2  = (const float*)d_in[7];
    const float* bhh2  = (const float*)d_in[8];
    const float* Wlin  = (const float*)d_in[9];
    const float* blin  = (const float*)d_in[10];
    float* out = (float*)d_out;

    const size_t TB = (size_t)Bb * Tt;
    const size_t packFloats = 204 * 52 + 204 * 104 + 3 * 204;
    const size_t needBig = (2 * TB + packFloats) * sizeof(float);

    float* ws = (float*)d_ws;

    // allow >64KB dynamic LDS (153,920 B)
    static bool attr_set = false;
    if (!attr_set) {
        hipFuncSetAttribute((const void*)lstm2,
                            hipFuncAttributeMaxDynamicSharedMemorySize,
                            LDS_TOT * (int)sizeof(float));
        attr_set = true;
    }
    const size_t ldsBytes = LDS_TOT * sizeof(float);

    if (ws_size >= needBig) {
        float* xT   = ws;
        float* yT   = ws + TB;
        float* W1p  = ws + 2 * TB;
        float* W2p  = W1p + 204 * 52;
        float* wx1  = W2p + 204 * 104;
        float* bs1  = wx1 + 204;
        float* bs2  = bs1 + 204;

        pack_weights<<<204, 64, 0, stream>>>(Wih1, Whh1, bih1, bhh1,
                                             Wih2, Whh2, bih2, bhh2,
                                             W1p, W2p, wx1, bs1, bs2);
        transpose_k<<<dim3(Tt / 64, Bb / 64), dim3(64, 8), 0, stream>>>(input, xT, Bb, Tt);
        lstm2<<<dim3(Bb / NBATCH), dim3(NTH), ldsBytes, stream>>>(
            xT, W1p, W2p, wx1, bs1, bs2, Wlin, blin, yT, 1);
        transpose_k<<<dim3(Bb / 64, Tt / 64), dim3(64, 8), 0, stream>>>(yT, out, Tt, Bb);
    } else {
        // fallback: packed weights only, strided x/y access
        float* W1p  = ws;
        float* W2p  = W1p + 204 * 52;
        float* wx1  = W2p + 204 * 104;
        float* bs1  = wx1 + 204;
        float* bs2  = bs1 + 204;

        pack_weights<<<204, 64, 0, stream>>>(Wih1, Whh1, bih1, bhh1,
                                             Wih2, Whh2, bih2, bhh2,
                                             W1p, W2p, wx1, bs1, bs2);
        lstm2<<<dim3(Bb / NBATCH), dim3(NTH), ldsBytes, stream>>>(
            input, W1p, W2p, wx1, bs1, bs2, Wlin, blin, out, 0);
    }
}